// Round 22
// baseline (349.238 us; speedup 1.0000x reference)
//
#include <hip/hip_runtime.h>
#include <hip/hip_bf16.h>

typedef __attribute__((ext_vector_type(8))) short bf16x8;
typedef __attribute__((ext_vector_type(2))) float f32x2;
typedef __attribute__((ext_vector_type(4))) float f32x4;
typedef __attribute__((ext_vector_type(8))) unsigned short u16x8;

__device__ __forceinline__ unsigned short f2bf(float f) {
  union { float f; unsigned u; } v; v.f = f;
  unsigned r = v.u + 0x7FFFu + ((v.u >> 16) & 1u);
  return (unsigned short)(r >> 16);
}

__device__ __forceinline__ bf16x8 cvt8(f32x4 a, f32x4 b) {
  u16x8 o;
  o[0] = f2bf(a[0]); o[1] = f2bf(a[1]); o[2] = f2bf(a[2]); o[3] = f2bf(a[3]);
  o[4] = f2bf(b[0]); o[5] = f2bf(b[1]); o[6] = f2bf(b[2]); o[7] = f2bf(b[3]);
  union { u16x8 u; bf16x8 s; } c; c.u = o;
  return c.s;
}

// ---------------------------------------------------------------------------
// 128x128-tile NT GEMM body with FUSED fp32->bf16 input conversion (proven).
__device__ __forceinline__
void gemm128_body(const float* __restrict__ A, const float* __restrict__ B,
                  unsigned short* __restrict__ Cb,
                  const float* __restrict__ bias, const float* __restrict__ scale,
                  int M, int N, int K, int wg, int nwg,
                  unsigned short* As, unsigned short* Bs) {
  int nby = N >> 7;
  if ((nwg & 7) == 0) {
    int cpx = nwg >> 3;
    wg = (wg & 7) * cpx + (wg >> 3);
  }
  int bm = wg / nby, bn = wg % nby;
  int m0 = bm << 7, n0 = bn << 7;

  int tid = threadIdx.x;
  int w = tid >> 6, lane = tid & 63;
  int wave_m = (w >> 1) << 6;
  int wave_n = (w & 1) << 6;

  int srow = tid >> 3, c8 = tid & 7;
  int slot = c8 ^ (srow & 7);
  const float* Ag = A + (size_t)(m0 + srow) * K + c8 * 8;
  const float* Bg = B + (size_t)(n0 + srow) * K + c8 * 8;
  int dst = srow * 64 + slot * 8;

  int hi = lane >> 4, lo = lane & 15, e7 = lane & 7;
  int a_base[2], b_base[2];
#pragma unroll
  for (int kk = 0; kk < 2; ++kk) {
    int sl = ((kk << 2) + hi) ^ e7;
    a_base[kk] = (wave_m + lo) * 64 + sl * 8;
    b_base[kk] = (wave_n + lo) * 64 + sl * 8;
  }

  f32x4 acc[4][4] = {};
  f32x4 ra[4][2], rb[4][2];

#define LOADK(KT)                                                         \
  {                                                                       \
    _Pragma("unroll") for (int i_ = 0; i_ < 4; ++i_) {                    \
      const float* pa = Ag + (size_t)(KT) * 64 + (size_t)(i_ * 32) * K;   \
      const float* pb = Bg + (size_t)(KT) * 64 + (size_t)(i_ * 32) * K;   \
      ra[i_][0] = *(const f32x4*)pa; ra[i_][1] = *(const f32x4*)(pa + 4); \
      rb[i_][0] = *(const f32x4*)pb; rb[i_][1] = *(const f32x4*)(pb + 4); \
    }                                                                     \
  }

  LOADK(0);
  int ksteps = K >> 6;
  for (int kt = 0; kt < ksteps; ++kt) {
#pragma unroll
    for (int i = 0; i < 4; ++i) {
      *(bf16x8*)(&As[dst + i * 2048]) = cvt8(ra[i][0], ra[i][1]);
      *(bf16x8*)(&Bs[dst + i * 2048]) = cvt8(rb[i][0], rb[i][1]);
    }
    __syncthreads();
    if (kt + 1 < ksteps) LOADK(kt + 1);

    bf16x8 afr[4][2], bfr[4][2];
#pragma unroll
    for (int kk = 0; kk < 2; ++kk) {
#pragma unroll
      for (int t2 = 0; t2 < 4; ++t2) {
        afr[t2][kk] = *(const bf16x8*)(&As[a_base[kk] + t2 * 1024]);
        bfr[t2][kk] = *(const bf16x8*)(&Bs[b_base[kk] + t2 * 1024]);
      }
    }
#pragma unroll
    for (int kk = 0; kk < 2; ++kk) {
#pragma unroll
      for (int mt = 0; mt < 4; ++mt) {
#pragma unroll
        for (int nt = 0; nt < 4; ++nt) {
          acc[mt][nt] = __builtin_amdgcn_mfma_f32_16x16x32_bf16(
              afr[mt][kk], bfr[nt][kk], acc[mt][nt], 0, 0, 0);
        }
      }
    }
    __syncthreads();
  }
#undef LOADK

  float bi[4], sc[4];
#pragma unroll
  for (int nt = 0; nt < 4; ++nt) {
    int n = n0 + wave_n + nt * 16 + lo;
    bi[nt] = bias ? bias[n] : 0.f;
    sc[nt] = scale ? scale[n] : 1.f;
  }
#pragma unroll
  for (int mt = 0; mt < 4; ++mt) {
#pragma unroll
    for (int r = 0; r < 4; ++r) {
      size_t m = (size_t)(m0 + wave_m + mt * 16 + hi * 4 + r);
      unsigned short* rowp = Cb + m * (size_t)N + (n0 + wave_n + lo);
#pragma unroll
      for (int nt = 0; nt < 4; ++nt) {
        float v = fmaxf(acc[mt][nt][r] + bi[nt], 0.f) * sc[nt];
        rowp[nt * 16] = f2bf(v);
      }
    }
  }
}

__global__ __launch_bounds__(256, 2)
void gemm_small_fused(const float* __restrict__ h, const float* __restrict__ Wh,
                      unsigned short* __restrict__ hawbf,
                      const float* __restrict__ bh, const float* __restrict__ w,
                      const float* __restrict__ l, const float* __restrict__ Wl,
                      unsigned short* __restrict__ labf,
                      const float* __restrict__ bl) {
  __shared__ unsigned short As[128 * 64];
  __shared__ unsigned short Bs[128 * 64];
  int bid = blockIdx.x;
  if (bid < 128) {
    gemm128_body(h, Wh, hawbf, bh, w, 4096, 512, 1024, bid, 128, As, Bs);
  } else {
    gemm128_body(l, Wl, labf, bl, nullptr, 32000, 512, 512, bid - 128, 1000, As, Bs);
  }
}

// ---------------------------------------------------------------------------
// MAIN GEMM: C[4096][32000] = A[4096][512] @ B[32000][512]^T + b.
// r22 = r21 (nt C stores) + DIRECT-A from L2 (third attempt, both prior
// failure causes removed):
//   - r13/r16 failed because C polluted L2 (FETCH 144 MB -> A refetched from
//     HBM at 900 cyc). nt stores (r21, -58 us) keep C out of the caches, so
//     A (512 KB/XCD via XCD-chunked order) is now genuinely L2-resident.
//   - A reg-loads issue at the TOP of the iteration, before STAGE_B, with
//     sched_barrier(0) before __syncthreads() so they can't sink; the
//     barrier's vmcnt(0) drain absorbs A's ~200cy L2 latency UNDER B's
//     longer L3 stage latency -> A never on the critical path.
//   - Halves K-loop LDS-port traffic (96 -> 48 KB/block-step), which the
//     cycle model says is the binding resource (~150 us of LDS time at r21).
// LDS 17 KiB (B 16 KiB + tbuf overlay). 4 blocks/CU.
__global__ __launch_bounds__(256, 4)
void gemm_main(const unsigned short* __restrict__ A,
               const unsigned short* __restrict__ B,
               float* __restrict__ Cf,
               const float* __restrict__ bconst) {
  constexpr int K = 512;
  constexpr int N = 32000;
  __shared__ __align__(16) char smem[17408];
  unsigned short* Bs = (unsigned short*)smem;   // 128x64 bf16 = 16 KiB
  float* tbuf = (float*)smem;   // epilogue overlay: 32 rows x 132 f32

  int bid = blockIdx.x;           // 8000 = 8 chunks x (250 bn x 4 bm-local)
  int chunk = bid & 7;
  int c = bid >> 3;               // 0..999
  int bm = chunk * 4 + (c & 3);   // 0..31
  int bn = c >> 2;                // 0..249
  size_t m0 = (size_t)bm * 128, n0 = (size_t)bn * 128;

  int tid = threadIdx.x;
  int lane = tid & 63;
  int wid = tid >> 6;
  int wm = wid >> 1, wn = wid & 1;          // 2x2 waves, 64x64 each
  int lo = lane & 15, hi = lane >> 4;

  // B staging: pre-swizzled global source, linear LDS dest (16B/lane)
  int srow = tid >> 3;                      // 0..31
  int kc = (tid & 7) ^ (srow & 7);
  const unsigned short* Bsrc = B + (n0 + srow) * K + kc * 8;
  int ldst = tid * 8;

  int soff[2];
  soff[0] = (hi ^ (lo & 7)) * 8;
  soff[1] = ((4 + hi) ^ (lo & 7)) * 8;

  // A direct-from-global (L2-hot): lane (lo,hi) owns row m0+wm*64+mt*16+lo,
  // 16 B at k-chunk kt*64 + kk*32 + hi*8 (4-lane hi-groups: 64 B contiguous).
  const unsigned short* Abase = A + (m0 + wm * 64 + lo) * (size_t)K + hi * 8;

  f32x4 acc[4][4] = {};

  for (int kt = 0; kt < 8; ++kt) {
    // 1) issue A register loads FIRST (latency absorbed at the barrier drain)
    bf16x8 areg[4][2];
#pragma unroll
    for (int mt = 0; mt < 4; ++mt)
#pragma unroll
      for (int kk = 0; kk < 2; ++kk)
        areg[mt][kk] = *(const bf16x8*)(Abase + (size_t)(mt * 16) * K +
                                        kt * 64 + kk * 32);
    // 2) issue B staging
    {
      const unsigned short* Bk = Bsrc + kt * 64;
#pragma unroll
      for (int i = 0; i < 4; ++i) {
        __builtin_amdgcn_global_load_lds(
            (const __attribute__((address_space(1))) void*)(
                Bk + (size_t)(i * 32) * K),
            (__attribute__((address_space(3))) void*)(Bs + i * 2048 + ldst),
            16, 0, 0);
      }
    }
    __builtin_amdgcn_sched_barrier(0);  // pin all issues BEFORE the barrier
    __syncthreads();  // vmcnt(0) drain: A regs + staged B both complete here

#pragma unroll
    for (int kk = 0; kk < 2; ++kk) {
      bf16x8 bfr[4];
#pragma unroll
      for (int nt = 0; nt < 4; ++nt)
        bfr[nt] = *(const bf16x8*)(&Bs[(wn * 64 + nt * 16 + lo) * 64 + soff[kk]]);
#pragma unroll
      for (int mt = 0; mt < 4; ++mt)
#pragma unroll
        for (int nt = 0; nt < 4; ++nt)
          acc[mt][nt] = __builtin_amdgcn_mfma_f32_16x16x32_bf16(
              areg[mt][kk], bfr[nt], acc[mt][nt], 0, 0, 0);
    }
    __syncthreads();  // Bs reads done before next-iter staging
  }

  // ---- LDS-transpose epilogue: 4 slabs of 32 rows x 128 cols (nt stores) ----
  float badd = bconst[0];
  for (int s = 0; s < 4; ++s) {
    if (wm == (s >> 1)) {
#pragma unroll
      for (int t = 0; t < 2; ++t) {
        int mt = (s & 1) * 2 + t;
#pragma unroll
        for (int nt = 0; nt < 4; ++nt)
#pragma unroll
          for (int r = 0; r < 4; ++r) {
            int rowl = t * 16 + hi * 4 + r;
            tbuf[rowl * 132 + wn * 64 + nt * 16 + lo] = acc[mt][nt][r] + badd;
          }
      }
    }
    __syncthreads();
    {
      size_t mrow = m0 + s * 32 + wid * 8;
#pragma unroll
      for (int q = 0; q < 8; ++q) {
        f32x2 v = *(const f32x2*)(&tbuf[(wid * 8 + q) * 132 + lane * 2]);
        __builtin_nontemporal_store(
            v, (f32x2*)(Cf + (mrow + q) * (size_t)N + n0 + lane * 2));
      }
    }
    __syncthreads();
  }
}

extern "C" void kernel_launch(void* const* d_in, const int* in_sizes, int n_in,
                              void* d_out, int out_size, void* d_ws, size_t ws_size,
                              hipStream_t stream) {
  const float* h  = (const float*)d_in[0];  // [4096,1024]
  const float* l  = (const float*)d_in[1];  // [32000,512]
  const float* Wh = (const float*)d_in[2];  // [512,1024]
  const float* bh = (const float*)d_in[3];  // [512]
  const float* Wl = (const float*)d_in[4];  // [512,512]
  const float* bl = (const float*)d_in[5];  // [512]
  const float* w  = (const float*)d_in[6];  // [512]
  const float* b  = (const float*)d_in[7];  // [1]
  float* out = (float*)d_out;               // [4096,32000]

  char* ws = (char*)d_ws;
  unsigned short* hawbf = (unsigned short*)(ws + 0);        //  4,194,304 B
  unsigned short* labf  = (unsigned short*)(ws + 4194304);  // 32,768,000 B

  // GEMM1 (128 blocks) + GEMM2 (1000 blocks) in one launch
  gemm_small_fused<<<dim3(1128), dim3(256), 0, stream>>>(
      h, Wh, hawbf, bh, w, l, Wl, labf, bl);
  // main: out = hawbf @ labf^T + b — nt-C + direct-A-from-L2, B via LDS
  gemm_main<<<dim3(8000), dim3(256), 0, stream>>>(hawbf, labf, out, b);
}

// Round 23
// 198.898 us; speedup vs baseline: 1.7559x; 1.7559x over previous
//
#include <hip/hip_runtime.h>
#include <hip/hip_bf16.h>

typedef __attribute__((ext_vector_type(8))) short bf16x8;
typedef __attribute__((ext_vector_type(2))) float f32x2;
typedef __attribute__((ext_vector_type(4))) float f32x4;
typedef __attribute__((ext_vector_type(8))) unsigned short u16x8;

__device__ __forceinline__ unsigned short f2bf(float f) {
  union { float f; unsigned u; } v; v.f = f;
  unsigned r = v.u + 0x7FFFu + ((v.u >> 16) & 1u);
  return (unsigned short)(r >> 16);
}

__device__ __forceinline__ bf16x8 cvt8(f32x4 a, f32x4 b) {
  u16x8 o;
  o[0] = f2bf(a[0]); o[1] = f2bf(a[1]); o[2] = f2bf(a[2]); o[3] = f2bf(a[3]);
  o[4] = f2bf(b[0]); o[5] = f2bf(b[1]); o[6] = f2bf(b[2]); o[7] = f2bf(b[3]);
  union { u16x8 u; bf16x8 s; } c; c.u = o;
  return c.s;
}

// ---------------------------------------------------------------------------
// 128x128-tile NT GEMM body with FUSED fp32->bf16 input conversion (proven).
__device__ __forceinline__
void gemm128_body(const float* __restrict__ A, const float* __restrict__ B,
                  unsigned short* __restrict__ Cb,
                  const float* __restrict__ bias, const float* __restrict__ scale,
                  int M, int N, int K, int wg, int nwg,
                  unsigned short* As, unsigned short* Bs) {
  int nby = N >> 7;
  if ((nwg & 7) == 0) {
    int cpx = nwg >> 3;
    wg = (wg & 7) * cpx + (wg >> 3);
  }
  int bm = wg / nby, bn = wg % nby;
  int m0 = bm << 7, n0 = bn << 7;

  int tid = threadIdx.x;
  int w = tid >> 6, lane = tid & 63;
  int wave_m = (w >> 1) << 6;
  int wave_n = (w & 1) << 6;

  int srow = tid >> 3, c8 = tid & 7;
  int slot = c8 ^ (srow & 7);
  const float* Ag = A + (size_t)(m0 + srow) * K + c8 * 8;
  const float* Bg = B + (size_t)(n0 + srow) * K + c8 * 8;
  int dst = srow * 64 + slot * 8;

  int hi = lane >> 4, lo = lane & 15, e7 = lane & 7;
  int a_base[2], b_base[2];
#pragma unroll
  for (int kk = 0; kk < 2; ++kk) {
    int sl = ((kk << 2) + hi) ^ e7;
    a_base[kk] = (wave_m + lo) * 64 + sl * 8;
    b_base[kk] = (wave_n + lo) * 64 + sl * 8;
  }

  f32x4 acc[4][4] = {};
  f32x4 ra[4][2], rb[4][2];

#define LOADK(KT)                                                         \
  {                                                                       \
    _Pragma("unroll") for (int i_ = 0; i_ < 4; ++i_) {                    \
      const float* pa = Ag + (size_t)(KT) * 64 + (size_t)(i_ * 32) * K;   \
      const float* pb = Bg + (size_t)(KT) * 64 + (size_t)(i_ * 32) * K;   \
      ra[i_][0] = *(const f32x4*)pa; ra[i_][1] = *(const f32x4*)(pa + 4); \
      rb[i_][0] = *(const f32x4*)pb; rb[i_][1] = *(const f32x4*)(pb + 4); \
    }                                                                     \
  }

  LOADK(0);
  int ksteps = K >> 6;
  for (int kt = 0; kt < ksteps; ++kt) {
#pragma unroll
    for (int i = 0; i < 4; ++i) {
      *(bf16x8*)(&As[dst + i * 2048]) = cvt8(ra[i][0], ra[i][1]);
      *(bf16x8*)(&Bs[dst + i * 2048]) = cvt8(rb[i][0], rb[i][1]);
    }
    __syncthreads();
    if (kt + 1 < ksteps) LOADK(kt + 1);

    bf16x8 afr[4][2], bfr[4][2];
#pragma unroll
    for (int kk = 0; kk < 2; ++kk) {
#pragma unroll
      for (int t2 = 0; t2 < 4; ++t2) {
        afr[t2][kk] = *(const bf16x8*)(&As[a_base[kk] + t2 * 1024]);
        bfr[t2][kk] = *(const bf16x8*)(&Bs[b_base[kk] + t2 * 1024]);
      }
    }
#pragma unroll
    for (int kk = 0; kk < 2; ++kk) {
#pragma unroll
      for (int mt = 0; mt < 4; ++mt) {
#pragma unroll
        for (int nt = 0; nt < 4; ++nt) {
          acc[mt][nt] = __builtin_amdgcn_mfma_f32_16x16x32_bf16(
              afr[mt][kk], bfr[nt][kk], acc[mt][nt], 0, 0, 0);
        }
      }
    }
    __syncthreads();
  }
#undef LOADK

  float bi[4], sc[4];
#pragma unroll
  for (int nt = 0; nt < 4; ++nt) {
    int n = n0 + wave_n + nt * 16 + lo;
    bi[nt] = bias ? bias[n] : 0.f;
    sc[nt] = scale ? scale[n] : 1.f;
  }
#pragma unroll
  for (int mt = 0; mt < 4; ++mt) {
#pragma unroll
    for (int r = 0; r < 4; ++r) {
      size_t m = (size_t)(m0 + wave_m + mt * 16 + hi * 4 + r);
      unsigned short* rowp = Cb + m * (size_t)N + (n0 + wave_n + lo);
#pragma unroll
      for (int nt = 0; nt < 4; ++nt) {
        float v = fmaxf(acc[mt][nt][r] + bi[nt], 0.f) * sc[nt];
        rowp[nt * 16] = f2bf(v);
      }
    }
  }
}

__global__ __launch_bounds__(256, 2)
void gemm_small_fused(const float* __restrict__ h, const float* __restrict__ Wh,
                      unsigned short* __restrict__ hawbf,
                      const float* __restrict__ bh, const float* __restrict__ w,
                      const float* __restrict__ l, const float* __restrict__ Wl,
                      unsigned short* __restrict__ labf,
                      const float* __restrict__ bl) {
  __shared__ unsigned short As[128 * 64];
  __shared__ unsigned short Bs[128 * 64];
  int bid = blockIdx.x;
  if (bid < 128) {
    gemm128_body(h, Wh, hawbf, bh, w, 4096, 512, 1024, bid, 128, As, Bs);
  } else {
    gemm128_body(l, Wl, labf, bl, nullptr, 32000, 512, 512, bid - 128, 1000, As, Bs);
  }
}

// ---------------------------------------------------------------------------
// MAIN GEMM: C[4096][32000] = A[4096][512] @ B[32000][512]^T + b.
// r23 = r21 restored (SESSION OPTIMUM, 199.3 us):
//   m97 geometry (BM=BN=128, BK=64, 256 thr / 4 waves, 32 KiB LDS),
//   __syncthreads() discipline, global_load_lds width-16 + XOR swizzle,
//   XCD-chunked block order, LDS-transpose epilogue (512 B contiguous per
//   store instr), 4 blocks/CU, NON-TEMPORAL C stores (the -58 us lever:
//   keeps the 524 MB write stream out of L2/L3 so A/B stay cache-resident).
// Refuted branches (do not retry): counted-vmcnt dbuf (r17-r19: deterministic
// race under 3 fence disciplines); direct-A-from-L2 (r13/r16/r22: FETCH
// 140-206 MB — A thrashes L2 even with nt-C; compiler re-sinks "prefetch"
// loads onto the MFMA path, VGPR=64); 8-phase/persistent/BM=256 (regressed).
__global__ __launch_bounds__(256, 4)
void gemm_main(const unsigned short* __restrict__ A,
               const unsigned short* __restrict__ B,
               float* __restrict__ Cf,
               const float* __restrict__ bconst) {
  constexpr int K = 512;
  constexpr int N = 32000;
  __shared__ __align__(16) char smem[32768];
  unsigned short* As = (unsigned short*)smem;            // 128x64 bf16 = 16 KiB
  unsigned short* Bs = (unsigned short*)(smem + 16384);  // 128x64 bf16 = 16 KiB
  float* tbuf = (float*)smem;  // epilogue overlay: 32 rows x 132 f32 (16.9 KiB)

  int bid = blockIdx.x;           // 8000 = 8 chunks x (250 bn x 4 bm-local)
  int chunk = bid & 7;
  int c = bid >> 3;               // 0..999
  int bm = chunk * 4 + (c & 3);   // 0..31
  int bn = c >> 2;                // 0..249
  size_t m0 = (size_t)bm * 128, n0 = (size_t)bn * 128;

  int tid = threadIdx.x;
  int lane = tid & 63;
  int wid = tid >> 6;
  int wm = wid >> 1, wn = wid & 1;          // 2x2 waves, 64x64 each
  int lo = lane & 15, hi = lane >> 4;

  // staging: pre-swizzled global source, linear LDS dest (16B/lane)
  int srow = tid >> 3;                      // 0..31
  int kc = (tid & 7) ^ (srow & 7);
  const unsigned short* Asrc = A + (m0 + srow) * K + kc * 8;
  const unsigned short* Bsrc = B + (n0 + srow) * K + kc * 8;
  int ldst = tid * 8;                       // + i*2048 per 32-row sub-load

  int soff[2];
  soff[0] = (hi ^ (lo & 7)) * 8;
  soff[1] = ((4 + hi) ^ (lo & 7)) * 8;

  f32x4 acc[4][4] = {};

  for (int kt = 0; kt < K / 64; ++kt) {
    const unsigned short* Ak = Asrc + kt * 64;
    const unsigned short* Bk = Bsrc + kt * 64;
#pragma unroll
    for (int i = 0; i < 4; ++i) {
      __builtin_amdgcn_global_load_lds(
          (const __attribute__((address_space(1))) void*)(Ak + (size_t)(i * 32) * K),
          (__attribute__((address_space(3))) void*)(As + i * 2048 + ldst),
          16, 0, 0);
    }
#pragma unroll
    for (int i = 0; i < 4; ++i) {
      __builtin_amdgcn_global_load_lds(
          (const __attribute__((address_space(1))) void*)(Bk + (size_t)(i * 32) * K),
          (__attribute__((address_space(3))) void*)(Bs + i * 2048 + ldst),
          16, 0, 0);
    }
    __syncthreads();  // drains vmcnt(0): staged data visible

#pragma unroll
    for (int kk = 0; kk < 2; ++kk) {
      bf16x8 afr[4], bfr[4];
#pragma unroll
      for (int mt = 0; mt < 4; ++mt)
        afr[mt] = *(const bf16x8*)(&As[(wm * 64 + mt * 16 + lo) * 64 + soff[kk]]);
#pragma unroll
      for (int nt = 0; nt < 4; ++nt)
        bfr[nt] = *(const bf16x8*)(&Bs[(wn * 64 + nt * 16 + lo) * 64 + soff[kk]]);
#pragma unroll
      for (int mt = 0; mt < 4; ++mt)
#pragma unroll
        for (int nt = 0; nt < 4; ++nt)
          acc[mt][nt] = __builtin_amdgcn_mfma_f32_16x16x32_bf16(
              afr[mt], bfr[nt], acc[mt][nt], 0, 0, 0);
    }
    __syncthreads();  // reads done before next-iter staging
  }

  // ---- LDS-transpose epilogue: 4 slabs of 32 rows x 128 cols ----
  float badd = bconst[0];
  for (int s = 0; s < 4; ++s) {
    if (wm == (s >> 1)) {   // the two waves owning this slab stage their acc
#pragma unroll
      for (int t = 0; t < 2; ++t) {
        int mt = (s & 1) * 2 + t;
#pragma unroll
        for (int nt = 0; nt < 4; ++nt)
#pragma unroll
          for (int r = 0; r < 4; ++r) {
            int rowl = t * 16 + hi * 4 + r;
            tbuf[rowl * 132 + wn * 64 + nt * 16 + lo] = acc[mt][nt][r] + badd;
          }
      }
    }
    __syncthreads();
    // each wave streams 8 full rows: 512 B contiguous per instruction (nt)
    {
      size_t mrow = m0 + s * 32 + wid * 8;
#pragma unroll
      for (int q = 0; q < 8; ++q) {
        f32x2 v = *(const f32x2*)(&tbuf[(wid * 8 + q) * 132 + lane * 2]);
        __builtin_nontemporal_store(
            v, (f32x2*)(Cf + (mrow + q) * (size_t)N + n0 + lane * 2));
      }
    }
    __syncthreads();
  }
}

extern "C" void kernel_launch(void* const* d_in, const int* in_sizes, int n_in,
                              void* d_out, int out_size, void* d_ws, size_t ws_size,
                              hipStream_t stream) {
  const float* h  = (const float*)d_in[0];  // [4096,1024]
  const float* l  = (const float*)d_in[1];  // [32000,512]
  const float* Wh = (const float*)d_in[2];  // [512,1024]
  const float* bh = (const float*)d_in[3];  // [512]
  const float* Wl = (const float*)d_in[4];  // [512,512]
  const float* bl = (const float*)d_in[5];  // [512]
  const float* w  = (const float*)d_in[6];  // [512]
  const float* b  = (const float*)d_in[7];  // [1]
  float* out = (float*)d_out;               // [4096,32000]

  char* ws = (char*)d_ws;
  unsigned short* hawbf = (unsigned short*)(ws + 0);        //  4,194,304 B
  unsigned short* labf  = (unsigned short*)(ws + 4194304);  // 32,768,000 B

  // GEMM1 (128 blocks) + GEMM2 (1000 blocks) in one launch
  gemm_small_fused<<<dim3(1128), dim3(256), 0, stream>>>(
      h, Wh, hawbf, bh, w, l, Wl, labf, bl);
  // main: out = hawbf @ labf^T + b — r12 structure + non-temporal C stores
  gemm_main<<<dim3(8000), dim3(256), 0, stream>>>(hawbf, labf, out, b);
}